// Round 1
// baseline (1249.457 us; speedup 1.0000x reference)
//
#include <hip/hip_runtime.h>

// Problem constants
#define BB 4
#define SS 2048
#define DD 1024
#define HH 16
#define HD 64
#define MM (BB*SS)   // 8192 rows

typedef unsigned short ushort_t;
typedef __attribute__((ext_vector_type(8))) short short8;
typedef __attribute__((ext_vector_type(4))) float f32x4;

__device__ __forceinline__ ushort_t f2bf(float f) {
    union { float f; unsigned u; } x; x.f = f;
    unsigned r = x.u + 0x7fffu + ((x.u >> 16) & 1u);
    return (ushort_t)(r >> 16);
}

// ---------------- Kernel 1: convert 4 weight matrices fp32 -> bf16 ----------
__global__ void cvt_weights(const float* __restrict__ wq, const float* __restrict__ wk,
                            const float* __restrict__ wv, const float* __restrict__ wo,
                            ushort_t* __restrict__ dst) {
    int i = blockIdx.x * 256 + threadIdx.x;       // 0 .. 4*1048576-1
    int w = i >> 20;
    int j = i & 1048575;
    const float* src = (w == 0) ? wq : (w == 1) ? wk : (w == 2) ? wv : wo;
    dst[i] = f2bf(src[j]);
}

// ---------------- Projection GEMM: Y = X(f32) . W(bf16)^T ------------------
// Wave tile: 16 (M) x 64 (N).  MODE 0: store [B,H,S,HD]; MODE 1: store [B,H,HD,S]
template<int MODE>
__global__ __launch_bounds__(256) void proj_gemm(const float* __restrict__ X,
                                                 const ushort_t* __restrict__ W,
                                                 ushort_t* __restrict__ Y) {
    int wid  = (blockIdx.x * 256 + threadIdx.x) >> 6;   // 0..8191
    int lane = threadIdx.x & 63;
    int l16  = lane & 15, quad = lane >> 4;
    int mt   = wid >> 4;             // 0..511
    int nb   = (wid & 15) * 64;      // n base

    int m = mt * 16 + l16;           // A-operand row
    const float* xrow = X + (size_t)m * DD + quad * 8;

    f32x4 zero = {0.f, 0.f, 0.f, 0.f};
    f32x4 acc[4] = {zero, zero, zero, zero};

    for (int k0 = 0; k0 < DD; k0 += 32) {
        float4 a0 = *(const float4*)(xrow + k0);
        float4 a1 = *(const float4*)(xrow + k0 + 4);
        short8 af;
        af[0] = (short)f2bf(a0.x); af[1] = (short)f2bf(a0.y);
        af[2] = (short)f2bf(a0.z); af[3] = (short)f2bf(a0.w);
        af[4] = (short)f2bf(a1.x); af[5] = (short)f2bf(a1.y);
        af[6] = (short)f2bf(a1.z); af[7] = (short)f2bf(a1.w);
        #pragma unroll
        for (int t = 0; t < 4; ++t) {
            short8 bf = *(const short8*)(W + (size_t)(nb + t*16 + l16) * DD + k0 + quad * 8);
            acc[t] = __builtin_amdgcn_mfma_f32_16x16x32_bf16(af, bf, acc[t], 0, 0, 0);
        }
    }

    #pragma unroll
    for (int t = 0; t < 4; ++t) {
        #pragma unroll
        for (int r = 0; r < 4; ++r) {
            int row = mt * 16 + quad * 4 + r;   // global m  (C layout: row = quad*4+reg)
            int col = nb + t * 16 + l16;        // global e  (C layout: col = lane&15)
            ushort_t v = f2bf(acc[t][r]);
            int b = row >> 11, s = row & 2047;
            int h = col >> 6,  hd = col & 63;
            if (MODE == 0)
                Y[(((size_t)b * HH + h) * SS + s) * HD + hd] = v;
            else
                Y[(((size_t)b * HH + h) * HD + hd) * SS + s] = v;
        }
    }
}

// ---------------- Output GEMM: out = A(bf16) . Wo(bf16)^T -> fp32 ----------
__global__ __launch_bounds__(256) void out_gemm(const ushort_t* __restrict__ Xbf,
                                                const ushort_t* __restrict__ W,
                                                float* __restrict__ Y) {
    int wid  = (blockIdx.x * 256 + threadIdx.x) >> 6;
    int lane = threadIdx.x & 63;
    int l16  = lane & 15, quad = lane >> 4;
    int mt   = wid >> 4;
    int nb   = (wid & 15) * 64;

    int m = mt * 16 + l16;
    const ushort_t* xrow = Xbf + (size_t)m * DD + quad * 8;

    f32x4 zero = {0.f, 0.f, 0.f, 0.f};
    f32x4 acc[4] = {zero, zero, zero, zero};

    for (int k0 = 0; k0 < DD; k0 += 32) {
        short8 af = *(const short8*)(xrow + k0);
        #pragma unroll
        for (int t = 0; t < 4; ++t) {
            short8 bf = *(const short8*)(W + (size_t)(nb + t*16 + l16) * DD + k0 + quad * 8);
            acc[t] = __builtin_amdgcn_mfma_f32_16x16x32_bf16(af, bf, acc[t], 0, 0, 0);
        }
    }

    #pragma unroll
    for (int t = 0; t < 4; ++t) {
        #pragma unroll
        for (int r = 0; r < 4; ++r) {
            int row = mt * 16 + quad * 4 + r;
            int col = nb + t * 16 + l16;
            Y[(size_t)row * DD + col] = acc[t][r];
        }
    }
}

// ---------------- Flash attention (causal, online softmax) -----------------
// Block = 4 waves = 64 q-rows of one (b,h). K-tiles of 64 keys.
__global__ __launch_bounds__(256) void attn_kernel(const ushort_t* __restrict__ xq,
                                                   const ushort_t* __restrict__ xk,
                                                   const ushort_t* __restrict__ xvT,
                                                   ushort_t* __restrict__ attno) {
    __shared__ __align__(16) ushort_t lds_p[4][16][72];   // +8 pad vs 64

    int w    = threadIdx.x >> 6;
    int lane = threadIdx.x & 63;
    int l16  = lane & 15, quad = lane >> 4;
    int qt   = blockIdx.x & 31;       // S/64 = 32 q-tiles
    int bh   = blockIdx.x >> 5;       // 0..63

    const ushort_t* Q  = xq  + (size_t)bh * SS * HD;
    const ushort_t* K  = xk  + (size_t)bh * SS * HD;
    const ushort_t* VT = xvT + (size_t)bh * HD * SS;

    int qrowA = qt * 64 + w * 16 + l16;        // A-operand row (query)
    short8 aq0 = *(const short8*)(Q + (size_t)qrowA * HD + quad * 8);
    short8 aq1 = *(const short8*)(Q + (size_t)qrowA * HD + 32 + quad * 8);

    f32x4 zero = {0.f, 0.f, 0.f, 0.f};
    f32x4 o[4] = {zero, zero, zero, zero};
    float mi[4] = {-1e30f, -1e30f, -1e30f, -1e30f};
    float li[4] = {0.f, 0.f, 0.f, 0.f};
    int qrowC = qt * 64 + w * 16 + quad * 4;   // C-layout row base (query)

    for (int kt = 0; kt <= qt; ++kt) {
        int kb = kt * 64;

        // ---- scores = Q . K^T   (16 q x 64 keys, 4 n-tiles) ----
        f32x4 sc[4];
        #pragma unroll
        for (int nt = 0; nt < 4; ++nt) {
            const ushort_t* krow = K + (size_t)(kb + nt*16 + l16) * HD + quad * 8;
            f32x4 c = zero;
            c = __builtin_amdgcn_mfma_f32_16x16x32_bf16(aq0, *(const short8*)krow,        c, 0, 0, 0);
            c = __builtin_amdgcn_mfma_f32_16x16x32_bf16(aq1, *(const short8*)(krow + 32), c, 0, 0, 0);
            sc[nt] = c;
        }

        // ---- mask + online softmax (rows live in C layout: row = quad*4+r) ----
        float p[4][4];
        #pragma unroll
        for (int r = 0; r < 4; ++r) {
            int qg = qrowC + r;
            float mx = -1e30f;
            #pragma unroll
            for (int nt = 0; nt < 4; ++nt) {
                int kg = kb + nt * 16 + l16;
                float s = sc[nt][r] * 0.125f;           // 1/sqrt(64)
                s = (kg <= qg) ? s : -1e30f;
                p[nt][r] = s;
                mx = fmaxf(mx, s);
            }
            #pragma unroll
            for (int off = 1; off < 16; off <<= 1)
                mx = fmaxf(mx, __shfl_xor(mx, off));
            float nm    = fmaxf(mi[r], mx);
            float alpha = __expf(mi[r] - nm);
            float rs = 0.f;
            #pragma unroll
            for (int nt = 0; nt < 4; ++nt) {
                float e = __expf(p[nt][r] - nm);
                p[nt][r] = e;
                rs += e;
            }
            #pragma unroll
            for (int off = 1; off < 16; off <<= 1)
                rs += __shfl_xor(rs, off);
            li[r] = li[r] * alpha + rs;
            mi[r] = nm;
            #pragma unroll
            for (int dt = 0; dt < 4; ++dt) o[dt][r] *= alpha;
        }

        // ---- P: C layout -> A layout via LDS round trip ----
        #pragma unroll
        for (int nt = 0; nt < 4; ++nt)
            #pragma unroll
            for (int r = 0; r < 4; ++r)
                lds_p[w][quad * 4 + r][nt * 16 + l16] = f2bf(p[nt][r]);
        __syncthreads();

        // ---- O += P . V   (V^T layout gives contiguous k loads) ----
        #pragma unroll
        for (int kc = 0; kc < 2; ++kc) {
            short8 ap = *(const short8*)&lds_p[w][l16][kc * 32 + quad * 8];
            #pragma unroll
            for (int dt = 0; dt < 4; ++dt) {
                const ushort_t* vrow = VT + (size_t)(dt*16 + l16) * SS + kb + kc * 32 + quad * 8;
                o[dt] = __builtin_amdgcn_mfma_f32_16x16x32_bf16(ap, *(const short8*)vrow, o[dt], 0, 0, 0);
            }
        }
        __syncthreads();
    }

    // ---- epilogue: divide by l, store [B,S,D] bf16 ----
    int b = bh >> 4, h = bh & 15;
    #pragma unroll
    for (int r = 0; r < 4; ++r) {
        float inv = 1.0f / li[r];
        int qg = qrowC + r;
        #pragma unroll
        for (int dt = 0; dt < 4; ++dt)
            attno[((size_t)(b * SS + qg)) * DD + h * HD + dt * 16 + l16] = f2bf(o[dt][r] * inv);
    }
}

// ---------------------------------------------------------------------------
extern "C" void kernel_launch(void* const* d_in, const int* in_sizes, int n_in,
                              void* d_out, int out_size, void* d_ws, size_t ws_size,
                              hipStream_t stream) {
    const float* q  = (const float*)d_in[0];
    const float* k  = (const float*)d_in[1];
    const float* v  = (const float*)d_in[2];
    const float* wq = (const float*)d_in[3];
    const float* wk = (const float*)d_in[4];
    const float* wv = (const float*)d_in[5];
    const float* wo = (const float*)d_in[6];
    float* out = (float*)d_out;

    // workspace layout (elements of ushort):
    // wbf[4*1M] | xq[8M] | xk[8M] | xvT[8M] | attno[8M]   -> 72 MB total
    ushort_t* wbf = (ushort_t*)d_ws;
    ushort_t* xq  = wbf + (size_t)4 * 1048576;
    ushort_t* xk  = xq  + (size_t)MM * DD;
    ushort_t* xvT = xk  + (size_t)MM * DD;
    ushort_t* ao  = xvT + (size_t)MM * DD;

    cvt_weights<<<16384, 256, 0, stream>>>(wq, wk, wv, wo, wbf);

    // 8192 wave-tiles (512 m-tiles x 16 n-groups), 4 waves/block
    proj_gemm<0><<<2048, 256, 0, stream>>>(q, wbf,               xq);
    proj_gemm<0><<<2048, 256, 0, stream>>>(k, wbf + 1048576,     xk);
    proj_gemm<1><<<2048, 256, 0, stream>>>(v, wbf + 2*1048576,   xvT);

    // B*H*(S/64) = 4*16*32 = 2048 blocks
    attn_kernel<<<2048, 256, 0, stream>>>(xq, xk, xvT, ao);

    out_gemm<<<2048, 256, 0, stream>>>(ao, wbf + 3*1048576, out);
}

// Round 2
// 521.546 us; speedup vs baseline: 2.3957x; 2.3957x over previous
//
#include <hip/hip_runtime.h>

#define SS 2048
#define DD 1024
#define HH 16
#define HD 64
#define MM 8192   // B*S

typedef unsigned short ushort_t;
typedef __attribute__((ext_vector_type(8))) short short8;
typedef __attribute__((ext_vector_type(4))) float f32x4;
typedef __attribute__((ext_vector_type(4))) unsigned short us4;

__device__ __forceinline__ ushort_t f2bf(float f) {
    union { float f; unsigned u; } x; x.f = f;
    unsigned r = x.u + 0x7fffu + ((x.u >> 16) & 1u);
    return (ushort_t)(r >> 16);
}

// async global->LDS, 16B per lane. LDS dst = wave-uniform base + lane*16.
__device__ __forceinline__ void async16(const void* g, void* l) {
    __builtin_amdgcn_global_load_lds(
        (const __attribute__((address_space(1))) unsigned int*)g,
        (__attribute__((address_space(3))) unsigned int*)l, 16, 0, 0);
}

// ---------------- cvt: fp32 -> bf16, 4 elems/thread --------------------------
__global__ void cvt_x(const float* __restrict__ src, ushort_t* __restrict__ dst) {
    int i = (blockIdx.x * 256 + threadIdx.x) * 4;
    float4 f = *(const float4*)(src + i);
    us4 o; o.x = f2bf(f.x); o.y = f2bf(f.y); o.z = f2bf(f.z); o.w = f2bf(f.w);
    *(us4*)(dst + i) = o;
}

__global__ void cvt_w(const float* __restrict__ wq, const float* __restrict__ wk,
                      const float* __restrict__ wv, const float* __restrict__ wo,
                      ushort_t* __restrict__ dst) {
    int i = (blockIdx.x * 256 + threadIdx.x) * 4;
    int w = i >> 20, j = i & 1048575;
    const float* src = (w == 0) ? wq : (w == 1) ? wk : (w == 2) ? wv : wo;
    float4 f = *(const float4*)(src + j);
    us4 o; o.x = f2bf(f.x); o.y = f2bf(f.y); o.z = f2bf(f.z); o.w = f2bf(f.w);
    *(us4*)(dst + i) = o;
}

// ---------------- 128x128 tiled GEMM: Y = A(bf16) . Bw(bf16)^T ---------------
// A: MxK row-major, Bw: NxK row-major (K contiguous both). BK=32.
// MODE 0: bf16 scatter [B,H,S,HD]; MODE 1: bf16 scatter [B,H,HD,S]; MODE 2: fp32 row-major
template<int MODE>
__global__ __launch_bounds__(256) void gemm128(const ushort_t* __restrict__ A,
                                               const ushort_t* __restrict__ Bw,
                                               void* __restrict__ Yv) {
    __shared__ __align__(16) ushort_t As[128 * 32];
    __shared__ __align__(16) ushort_t Bs[128 * 32];
    int tid  = threadIdx.x;
    int w    = tid >> 6, lane = tid & 63;
    int l16  = lane & 15, quad = lane >> 4;
    int m0   = (int)(blockIdx.x >> 3) * 128;
    int n0   = (int)(blockIdx.x & 7) * 128;
    int wm   = (w >> 1) * 64, wn = (w & 1) * 64;

    f32x4 acc[4][4];
    #pragma unroll
    for (int i = 0; i < 4; ++i)
        #pragma unroll
        for (int j = 0; j < 4; ++j) acc[i][j] = (f32x4){0.f, 0.f, 0.f, 0.f};

    // staging granules: 4 granules (16B) per 32-half row; XOR swizzle j^=(row&3)
    int g0 = w * 64 + lane,     r0 = g0 >> 2, j0 = ((g0 & 3) ^ (r0 & 3)) * 8;
    int g1 = g0 + 256,          r1 = g1 >> 2, j1 = ((g1 & 3) ^ (r1 & 3)) * 8;
    ushort_t* aD0 = As + (size_t)(w * 64) * 8;
    ushort_t* aD1 = As + (size_t)(256 + w * 64) * 8;
    ushort_t* bD0 = Bs + (size_t)(w * 64) * 8;
    ushort_t* bD1 = Bs + (size_t)(256 + w * 64) * 8;

    int swA = (quad ^ (l16 & 3)) * 8;   // physical granule offset (halves) for frag reads

    for (int k0 = 0; k0 < DD; k0 += 32) {
        __syncthreads();
        async16(A  + (size_t)(m0 + r0) * DD + k0 + j0, aD0);
        async16(A  + (size_t)(m0 + r1) * DD + k0 + j1, aD1);
        async16(Bw + (size_t)(n0 + r0) * DD + k0 + j0, bD0);
        async16(Bw + (size_t)(n0 + r1) * DD + k0 + j1, bD1);
        __syncthreads();

        short8 af[4], bfr[4];
        #pragma unroll
        for (int t = 0; t < 4; ++t) {
            af[t]  = *(const short8*)&As[(wm + t * 16 + l16) * 32 + swA];
            bfr[t] = *(const short8*)&Bs[(wn + t * 16 + l16) * 32 + swA];
        }
        #pragma unroll
        for (int mt = 0; mt < 4; ++mt)
            #pragma unroll
            for (int nt = 0; nt < 4; ++nt)
                acc[mt][nt] = __builtin_amdgcn_mfma_f32_16x16x32_bf16(af[mt], bfr[nt], acc[mt][nt], 0, 0, 0);
    }

    #pragma unroll
    for (int mt = 0; mt < 4; ++mt) {
        #pragma unroll
        for (int r = 0; r < 4; ++r) {
            int row = m0 + wm + mt * 16 + quad * 4 + r;
            #pragma unroll
            for (int nt = 0; nt < 4; ++nt) {
                int col = n0 + wn + nt * 16 + l16;
                float vf = acc[mt][nt][r];
                if (MODE == 2) {
                    ((float*)Yv)[(size_t)row * DD + col] = vf;
                } else {
                    ushort_t vh = f2bf(vf);
                    int b = row >> 11, s = row & 2047;
                    int h = col >> 6,  hd = col & 63;
                    if (MODE == 0)
                        ((ushort_t*)Yv)[(((size_t)b * HH + h) * SS + s) * HD + hd] = vh;
                    else
                        ((ushort_t*)Yv)[(((size_t)b * HH + h) * HD + hd) * SS + s] = vh;
                }
            }
        }
    }
}

// ---------------- Flash attention: 128 q-rows/block, 64-key tiles ------------
__global__ __launch_bounds__(256) void attn_kernel(const ushort_t* __restrict__ xq,
                                                   const ushort_t* __restrict__ xk,
                                                   const ushort_t* __restrict__ xvT,
                                                   ushort_t* __restrict__ ao) {
    __shared__ __align__(16) ushort_t Ksm[64 * 64];      // [key][d], XOR-swizzled granules
    __shared__ __align__(16) ushort_t Vsm[64 * 64];      // [d][key], XOR-swizzled granules
    __shared__ __align__(16) ushort_t Psm[4][32 * 80];   // per-wave P, stride 80 (16B-aligned)

    int tid  = threadIdx.x;
    int w    = tid >> 6, lane = tid & 63;
    int l16  = lane & 15, quad = lane >> 4;
    int qt   = blockIdx.x & 15;     // 16 q-tiles of 128
    int bh   = blockIdx.x >> 4;     // 0..63
    int qb   = qt * 128;

    const ushort_t* Q  = xq  + (size_t)bh * SS * HD;
    const ushort_t* K  = xk  + (size_t)bh * SS * HD;
    const ushort_t* VT = xvT + (size_t)bh * HD * SS;

    // Q fragments (held in regs): wave w owns rows qb+w*32 .. +31 (2 m-tiles)
    short8 aq[2][2];
    #pragma unroll
    for (int mt = 0; mt < 2; ++mt)
        #pragma unroll
        for (int kc = 0; kc < 2; ++kc)
            aq[mt][kc] = *(const short8*)(Q + (size_t)(qb + w * 32 + mt * 16 + l16) * HD + kc * 32 + quad * 8);

    f32x4 o[2][4];
    float mi[2][4], li[2][4];
    #pragma unroll
    for (int mt = 0; mt < 2; ++mt)
        #pragma unroll
        for (int r = 0; r < 4; ++r) {
            mi[mt][r] = -1e30f; li[mt][r] = 0.f;
            if (r == 0) { o[mt][0] = (f32x4){0,0,0,0}; o[mt][1] = (f32x4){0,0,0,0};
                          o[mt][2] = (f32x4){0,0,0,0}; o[mt][3] = (f32x4){0,0,0,0}; }
        }

    // staging granules: 8 granules per 64-half row; XOR swizzle j^=(row&7)
    int g0 = w * 64 + lane,  r0 = g0 >> 3, j0 = ((g0 & 7) ^ (r0 & 7)) * 8;
    int g1 = g0 + 256,       r1 = g1 >> 3, j1 = ((g1 & 7) ^ (r1 & 7)) * 8;
    ushort_t* kD0 = Ksm + (size_t)(w * 64) * 8;
    ushort_t* kD1 = Ksm + (size_t)(256 + w * 64) * 8;
    ushort_t* vD0 = Vsm + (size_t)(w * 64) * 8;
    ushort_t* vD1 = Vsm + (size_t)(256 + w * 64) * 8;

    int niter = 2 * qt + 2;
    for (int kt = 0; kt < niter; ++kt) {
        int kb = kt * 64;
        __syncthreads();
        async16(K  + (size_t)(kb + r0) * HD + j0, kD0);
        async16(K  + (size_t)(kb + r1) * HD + j1, kD1);
        async16(VT + (size_t)r0 * SS + kb + j0, vD0);
        async16(VT + (size_t)r1 * SS + kb + j1, vD1);
        __syncthreads();

        // ---- scores = Q . K^T ----
        f32x4 sc[2][4];
        #pragma unroll
        for (int nt = 0; nt < 4; ++nt) {
            int row = nt * 16 + l16;
            short8 bk0 = *(const short8*)&Ksm[row * 64 + ((0 + quad) ^ (l16 & 7)) * 8];
            short8 bk1 = *(const short8*)&Ksm[row * 64 + ((4 + quad) ^ (l16 & 7)) * 8];
            #pragma unroll
            for (int mt = 0; mt < 2; ++mt) {
                f32x4 c = (f32x4){0,0,0,0};
                c = __builtin_amdgcn_mfma_f32_16x16x32_bf16(aq[mt][0], bk0, c, 0, 0, 0);
                c = __builtin_amdgcn_mfma_f32_16x16x32_bf16(aq[mt][1], bk1, c, 0, 0, 0);
                sc[mt][nt] = c;
            }
        }

        // ---- online softmax (C layout: row = quad*4+r, col = nt*16+l16) ----
        #pragma unroll
        for (int mt = 0; mt < 2; ++mt) {
            #pragma unroll
            for (int r = 0; r < 4; ++r) {
                int qg = qb + w * 32 + mt * 16 + quad * 4 + r;
                float pv[4]; float mx = -1e30f;
                #pragma unroll
                for (int nt = 0; nt < 4; ++nt) {
                    int kg = kb + nt * 16 + l16;
                    float s = sc[mt][nt][r] * 0.125f;
                    s = (kg <= qg) ? s : -1e30f;
                    pv[nt] = s; mx = fmaxf(mx, s);
                }
                mx = fmaxf(mx, __shfl_xor(mx, 1));
                mx = fmaxf(mx, __shfl_xor(mx, 2));
                mx = fmaxf(mx, __shfl_xor(mx, 4));
                mx = fmaxf(mx, __shfl_xor(mx, 8));
                float nm    = fmaxf(mi[mt][r], mx);
                float alpha = __expf(mi[mt][r] - nm);
                float rs = 0.f;
                #pragma unroll
                for (int nt = 0; nt < 4; ++nt) {
                    float e = __expf(pv[nt] - nm);
                    Psm[w][(mt * 16 + quad * 4 + r) * 80 + nt * 16 + l16] = f2bf(e);
                    rs += e;
                }
                rs += __shfl_xor(rs, 1);
                rs += __shfl_xor(rs, 2);
                rs += __shfl_xor(rs, 4);
                rs += __shfl_xor(rs, 8);
                li[mt][r] = li[mt][r] * alpha + rs;
                mi[mt][r] = nm;
                #pragma unroll
                for (int dt = 0; dt < 4; ++dt) o[mt][dt][r] *= alpha;
            }
        }

        // per-wave P scratch: drain DS writes before reading (same wave, no barrier)
        asm volatile("s_waitcnt lgkmcnt(0)" ::: "memory");

        // ---- O += P . V ----
        #pragma unroll
        for (int kc = 0; kc < 2; ++kc) {
            short8 ap[2];
            #pragma unroll
            for (int mt = 0; mt < 2; ++mt)
                ap[mt] = *(const short8*)&Psm[w][(mt * 16 + l16) * 80 + kc * 32 + quad * 8];
            #pragma unroll
            for (int dt = 0; dt < 4; ++dt) {
                int row = dt * 16 + l16;
                short8 bv = *(const short8*)&Vsm[row * 64 + ((kc * 4 + quad) ^ (l16 & 7)) * 8];
                #pragma unroll
                for (int mt = 0; mt < 2; ++mt)
                    o[mt][dt] = __builtin_amdgcn_mfma_f32_16x16x32_bf16(ap[mt], bv, o[mt][dt], 0, 0, 0);
            }
        }
    }

    // ---- epilogue: divide by l, store [B,S,D] bf16 ----
    int b = bh >> 4, h = bh & 15;
    #pragma unroll
    for (int mt = 0; mt < 2; ++mt) {
        #pragma unroll
        for (int r = 0; r < 4; ++r) {
            float inv = 1.0f / li[mt][r];
            int qg = qb + w * 32 + mt * 16 + quad * 4 + r;
            #pragma unroll
            for (int dt = 0; dt < 4; ++dt)
                ao[((size_t)(b * SS + qg)) * DD + h * HD + dt * 16 + l16] = f2bf(o[mt][dt][r] * inv);
        }
    }
}

// ---------------------------------------------------------------------------
extern "C" void kernel_launch(void* const* d_in, const int* in_sizes, int n_in,
                              void* d_out, int out_size, void* d_ws, size_t ws_size,
                              hipStream_t stream) {
    const float* q  = (const float*)d_in[0];
    const float* k  = (const float*)d_in[1];
    const float* v  = (const float*)d_in[2];
    const float* wq = (const float*)d_in[3];
    const float* wk = (const float*)d_in[4];
    const float* wv = (const float*)d_in[5];
    const float* wo = (const float*)d_in[6];
    float* out = (float*)d_out;

    // ws layout (halves): wbf[4M] | xq[8M] | xk[8M] | xvT[8M] | xbuf[8M]  = 72 MB
    // xbuf doubles as: bf16 copy of q/k/v before each projection, then attn output.
    ushort_t* wbf  = (ushort_t*)d_ws;
    ushort_t* xq   = wbf + (size_t)4 * 1048576;
    ushort_t* xk   = xq  + (size_t)MM * DD;
    ushort_t* xvT  = xk  + (size_t)MM * DD;
    ushort_t* xbuf = xvT + (size_t)MM * DD;

    cvt_w<<<4096, 256, 0, stream>>>(wq, wk, wv, wo, wbf);

    cvt_x<<<8192, 256, 0, stream>>>(q, xbuf);
    gemm128<0><<<512, 256, 0, stream>>>(xbuf, wbf,               xq);
    cvt_x<<<8192, 256, 0, stream>>>(k, xbuf);
    gemm128<0><<<512, 256, 0, stream>>>(xbuf, wbf + 1048576,     xk);
    cvt_x<<<8192, 256, 0, stream>>>(v, xbuf);
    gemm128<1><<<512, 256, 0, stream>>>(xbuf, wbf + 2 * 1048576, xvT);

    attn_kernel<<<1024, 256, 0, stream>>>(xq, xk, xvT, xbuf);

    gemm128<2><<<512, 256, 0, stream>>>(xbuf, wbf + 3 * 1048576, out);
}

// Round 3
// 385.193 us; speedup vs baseline: 3.2437x; 1.3540x over previous
//
#include <hip/hip_runtime.h>

#define SS 2048
#define DD 1024
#define HH 16
#define HD 64
#define MM 8192   // B*S

typedef unsigned short ushort_t;
typedef __attribute__((ext_vector_type(8))) short short8;
typedef __attribute__((ext_vector_type(4))) float f32x4;
typedef __attribute__((ext_vector_type(4))) unsigned short us4;

__device__ __forceinline__ ushort_t f2bf(float f) {
    union { float f; unsigned u; } x; x.f = f;
    unsigned r = x.u + 0x7fffu + ((x.u >> 16) & 1u);
    return (ushort_t)(r >> 16);
}
__device__ __forceinline__ float bf2f(ushort_t h) {
    union { unsigned u; float f; } x; x.u = ((unsigned)h) << 16; return x.f;
}

// async global->LDS, 16B per lane. LDS dst = wave-uniform base + lane*16.
__device__ __forceinline__ void async16(const void* g, void* l) {
    __builtin_amdgcn_global_load_lds(
        (const __attribute__((address_space(1))) unsigned int*)g,
        (__attribute__((address_space(3))) unsigned int*)l, 16, 0, 0);
}

// ---------------- converters -------------------------------------------------
__global__ void cvt_w(const float* __restrict__ wq, const float* __restrict__ wk,
                      const float* __restrict__ wv, const float* __restrict__ wo,
                      ushort_t* __restrict__ dst) {
    int i = (blockIdx.x * 256 + threadIdx.x) * 4;
    int w = i >> 20, j = i & 1048575;
    const float* src = (w == 0) ? wq : (w == 1) ? wk : (w == 2) ? wv : wo;
    float4 f = *(const float4*)(src + j);
    us4 o; o.x = f2bf(f.x); o.y = f2bf(f.y); o.z = f2bf(f.z); o.w = f2bf(f.w);
    *(us4*)(dst + i) = o;
}

__global__ void cvt3(const float* __restrict__ q, const float* __restrict__ k,
                     const float* __restrict__ v, ushort_t* __restrict__ dst) {
    int i = (blockIdx.x * 256 + threadIdx.x) * 4;   // < 3 * 2^23
    int mat = i >> 23, j = i & ((1 << 23) - 1);
    const float* src = (mat == 0) ? q : (mat == 1) ? k : v;
    float4 f = *(const float4*)(src + j);
    us4 o; o.x = f2bf(f.x); o.y = f2bf(f.y); o.z = f2bf(f.z); o.w = f2bf(f.w);
    *(us4*)(dst + i) = o;
}

__global__ void cvt_x(const float* __restrict__ src, ushort_t* __restrict__ dst) {
    int i = (blockIdx.x * 256 + threadIdx.x) * 4;
    float4 f = *(const float4*)(src + i);
    us4 o; o.x = f2bf(f.x); o.y = f2bf(f.y); o.z = f2bf(f.z); o.w = f2bf(f.w);
    *(us4*)(dst + i) = o;
}

// ---------------- shared 128x128 GEMM core (BK=32, async LDS, XOR swizzle) ---
__device__ __forceinline__ void gemm_core(const ushort_t* __restrict__ A,
                                          const ushort_t* __restrict__ Bw,
                                          ushort_t* As, ushort_t* Bs,
                                          int m0, int n0, f32x4 acc[4][4]) {
    int tid = threadIdx.x;
    int w = tid >> 6, lane = tid & 63;
    int l16 = lane & 15, quad = lane >> 4;
    int wm = (w >> 1) * 64, wn = (w & 1) * 64;

    int g0 = w * 64 + lane, r0 = g0 >> 2, j0 = ((g0 & 3) ^ (r0 & 3)) * 8;
    int g1 = g0 + 256,      r1 = g1 >> 2, j1 = ((g1 & 3) ^ (r1 & 3)) * 8;
    ushort_t* aD0 = As + (size_t)(w * 64) * 8;
    ushort_t* aD1 = As + (size_t)(256 + w * 64) * 8;
    ushort_t* bD0 = Bs + (size_t)(w * 64) * 8;
    ushort_t* bD1 = Bs + (size_t)(256 + w * 64) * 8;
    int swA = (quad ^ (l16 & 3)) * 8;

    for (int k0 = 0; k0 < DD; k0 += 32) {
        __syncthreads();
        async16(A  + (size_t)(m0 + r0) * DD + k0 + j0, aD0);
        async16(A  + (size_t)(m0 + r1) * DD + k0 + j1, aD1);
        async16(Bw + (size_t)(n0 + r0) * DD + k0 + j0, bD0);
        async16(Bw + (size_t)(n0 + r1) * DD + k0 + j1, bD1);
        __syncthreads();

        short8 af[4], bfr[4];
        #pragma unroll
        for (int t = 0; t < 4; ++t) {
            af[t]  = *(const short8*)&As[(wm + t * 16 + l16) * 32 + swA];
            bfr[t] = *(const short8*)&Bs[(wn + t * 16 + l16) * 32 + swA];
        }
        #pragma unroll
        for (int mt = 0; mt < 4; ++mt)
            #pragma unroll
            for (int nt = 0; nt < 4; ++nt)
                acc[mt][nt] = __builtin_amdgcn_mfma_f32_16x16x32_bf16(af[mt], bfr[nt], acc[mt][nt], 0, 0, 0);
    }
}

__device__ __forceinline__ void epi_scatter(f32x4 acc[4][4], int m0, int n0,
                                            int mode, void* Yv) {
    int tid = threadIdx.x;
    int w = tid >> 6, lane = tid & 63;
    int l16 = lane & 15, quad = lane >> 4;
    int wm = (w >> 1) * 64, wn = (w & 1) * 64;
    #pragma unroll
    for (int mt = 0; mt < 4; ++mt) {
        #pragma unroll
        for (int r = 0; r < 4; ++r) {
            int row = m0 + wm + mt * 16 + quad * 4 + r;
            #pragma unroll
            for (int nt = 0; nt < 4; ++nt) {
                int col = n0 + wn + nt * 16 + l16;
                float vf = acc[mt][nt][r];
                if (mode == 2) {
                    ((float*)Yv)[(size_t)row * DD + col] = vf;
                } else {
                    ushort_t vh = f2bf(vf);
                    int b = row >> 11, s = row & 2047;
                    int h = col >> 6,  hd = col & 63;
                    if (mode == 0)
                        ((ushort_t*)Yv)[(((size_t)b * HH + h) * SS + s) * HD + hd] = vh;
                    else
                        ((ushort_t*)Yv)[(((size_t)b * HH + h) * HD + hd) * SS + s] = vh;
                }
            }
        }
    }
}

template<int MODE>
__global__ __launch_bounds__(256) void gemm128(const ushort_t* __restrict__ A,
                                               const ushort_t* __restrict__ Bw,
                                               void* __restrict__ Yv) {
    __shared__ __align__(16) ushort_t As[128 * 32];
    __shared__ __align__(16) ushort_t Bs[128 * 32];
    int m0 = (int)(blockIdx.x >> 3) * 128;
    int n0 = (int)(blockIdx.x & 7) * 128;
    f32x4 acc[4][4];
    #pragma unroll
    for (int i = 0; i < 4; ++i)
        #pragma unroll
        for (int j = 0; j < 4; ++j) acc[i][j] = (f32x4){0.f, 0.f, 0.f, 0.f};
    gemm_core(A, Bw, As, Bs, m0, n0, acc);
    epi_scatter(acc, m0, n0, MODE, Yv);
}

// fused q/k/v projections: 1536 blocks
__global__ __launch_bounds__(256) void proj3(const ushort_t* __restrict__ Xall,
                                             const ushort_t* __restrict__ Wall,
                                             ushort_t* __restrict__ xq,
                                             ushort_t* __restrict__ xk,
                                             ushort_t* __restrict__ xvT) {
    __shared__ __align__(16) ushort_t As[128 * 32];
    __shared__ __align__(16) ushort_t Bs[128 * 32];
    int mat = (int)(blockIdx.x >> 9);
    int inner = (int)(blockIdx.x & 511);
    int m0 = (inner >> 3) * 128;
    int n0 = (inner & 7) * 128;
    const ushort_t* A  = Xall + (size_t)mat * MM * DD;
    const ushort_t* Bw = Wall + ((size_t)mat << 20);
    f32x4 acc[4][4];
    #pragma unroll
    for (int i = 0; i < 4; ++i)
        #pragma unroll
        for (int j = 0; j < 4; ++j) acc[i][j] = (f32x4){0.f, 0.f, 0.f, 0.f};
    gemm_core(A, Bw, As, Bs, m0, n0, acc);
    void* Y = (mat == 0) ? (void*)xq : (mat == 1) ? (void*)xk : (void*)xvT;
    epi_scatter(acc, m0, n0, (mat == 2) ? 1 : 0, Y);
}

// ---------------- Flash attention: paired q-tiles for perfect balance --------
// 512 blocks = 64 bh x 8 pairs; block handles q-tiles (p, 15-p): 34 tile-iters each.
__global__ __launch_bounds__(256) void attn_kernel(const ushort_t* __restrict__ xq,
                                                   const ushort_t* __restrict__ xk,
                                                   const ushort_t* __restrict__ xvT,
                                                   ushort_t* __restrict__ ao) {
    __shared__ __align__(16) ushort_t Ksm[64 * 64];
    __shared__ __align__(16) ushort_t Vsm[64 * 64];
    __shared__ __align__(16) ushort_t Psm[4][32 * 88];   // stride 88: 2-way banks

    int tid = threadIdx.x;
    int w = tid >> 6, lane = tid & 63;
    int l16 = lane & 15, quad = lane >> 4;
    int p  = blockIdx.x & 7;
    int bh = blockIdx.x >> 3;
    int b = bh >> 4, h = bh & 15;

    const ushort_t* Q  = xq  + (size_t)bh * SS * HD;
    const ushort_t* K  = xk  + (size_t)bh * SS * HD;
    const ushort_t* VT = xvT + (size_t)bh * HD * SS;

    int g0 = w * 64 + lane, r0 = g0 >> 3, j0 = ((g0 & 7) ^ (r0 & 7)) * 8;
    int g1 = g0 + 256,      r1 = g1 >> 3, j1 = ((g1 & 7) ^ (r1 & 7)) * 8;
    ushort_t* kD0 = Ksm + (size_t)(w * 64) * 8;
    ushort_t* kD1 = Ksm + (size_t)(256 + w * 64) * 8;
    ushort_t* vD0 = Vsm + (size_t)(w * 64) * 8;
    ushort_t* vD1 = Vsm + (size_t)(256 + w * 64) * 8;

    const float CS = 0.125f * 1.44269504f;   // scale * log2(e), folded into Q

    for (int ph = 0; ph < 2; ++ph) {
        int qt = ph ? (15 - p) : p;
        int qb = qt * 128;
        int qmin = qb + w * 32;

        // Q fragments, pre-scaled by CS (once per phase, not per score)
        short8 aq[2][2];
        #pragma unroll
        for (int mt = 0; mt < 2; ++mt)
            #pragma unroll
            for (int kc = 0; kc < 2; ++kc) {
                short8 t = *(const short8*)(Q + (size_t)(qmin + mt * 16 + l16) * HD + kc * 32 + quad * 8);
                #pragma unroll
                for (int i = 0; i < 8; ++i)
                    t[i] = (short)f2bf(bf2f((ushort_t)t[i]) * CS);
                aq[mt][kc] = t;
            }

        f32x4 o[2][4];
        float mi[2][4], li[2][4];
        #pragma unroll
        for (int mt = 0; mt < 2; ++mt) {
            #pragma unroll
            for (int dt = 0; dt < 4; ++dt) o[mt][dt] = (f32x4){0.f, 0.f, 0.f, 0.f};
            #pragma unroll
            for (int r = 0; r < 4; ++r) { mi[mt][r] = -1e30f; li[mt][r] = 0.f; }
        }

        int niter = 2 * qt + 2;
        for (int kt = 0; kt < niter; ++kt) {
            int kb = kt * 64;
            __syncthreads();
            async16(K  + (size_t)(kb + r0) * HD + j0, kD0);
            async16(K  + (size_t)(kb + r1) * HD + j1, kD1);
            async16(VT + (size_t)r0 * SS + kb + j0, vD0);
            async16(VT + (size_t)r1 * SS + kb + j1, vD1);
            __syncthreads();

            if (kb > qmin + 31) continue;          // tile fully masked for this wave
            bool need_mask = (kb + 63 > qmin);     // wave-uniform

            // ---- scores = (CS*Q) . K^T  (already in log2 domain) ----
            f32x4 sc[2][4];
            #pragma unroll
            for (int nt = 0; nt < 4; ++nt) {
                int row = nt * 16 + l16;
                short8 bk0 = *(const short8*)&Ksm[row * 64 + ((0 + quad) ^ (l16 & 7)) * 8];
                short8 bk1 = *(const short8*)&Ksm[row * 64 + ((4 + quad) ^ (l16 & 7)) * 8];
                #pragma unroll
                for (int mt = 0; mt < 2; ++mt) {
                    f32x4 c = (f32x4){0.f, 0.f, 0.f, 0.f};
                    c = __builtin_amdgcn_mfma_f32_16x16x32_bf16(aq[mt][0], bk0, c, 0, 0, 0);
                    c = __builtin_amdgcn_mfma_f32_16x16x32_bf16(aq[mt][1], bk1, c, 0, 0, 0);
                    sc[mt][nt] = c;
                }
            }

            // ---- online softmax (exp2 domain, deferred l-reduction) ----
            #pragma unroll
            for (int mt = 0; mt < 2; ++mt) {
                #pragma unroll
                for (int r = 0; r < 4; ++r) {
                    float pv[4]; float mx = -1e30f;
                    #pragma unroll
                    for (int nt = 0; nt < 4; ++nt) {
                        float s = sc[mt][nt][r];
                        if (need_mask) {
                            int qg = qmin + mt * 16 + quad * 4 + r;
                            int kg = kb + nt * 16 + l16;
                            s = (kg <= qg) ? s : -1e30f;
                        }
                        pv[nt] = s; mx = fmaxf(mx, s);
                    }
                    mx = fmaxf(mx, __shfl_xor(mx, 1));
                    mx = fmaxf(mx, __shfl_xor(mx, 2));
                    mx = fmaxf(mx, __shfl_xor(mx, 4));
                    mx = fmaxf(mx, __shfl_xor(mx, 8));
                    float nm = fmaxf(mi[mt][r], mx);
                    float al = __builtin_amdgcn_exp2f(mi[mt][r] - nm);
                    float rs = 0.f;
                    #pragma unroll
                    for (int nt = 0; nt < 4; ++nt) {
                        float e = __builtin_amdgcn_exp2f(pv[nt] - nm);
                        Psm[w][(mt * 16 + quad * 4 + r) * 88 + nt * 16 + l16] = f2bf(e);
                        rs += e;
                    }
                    li[mt][r] = li[mt][r] * al + rs;   // per-lane partial sum
                    mi[mt][r] = nm;
                    #pragma unroll
                    for (int dt = 0; dt < 4; ++dt) o[mt][dt][r] *= al;
                }
            }

            // per-wave P scratch: drain DS writes before reads (no barrier needed)
            asm volatile("s_waitcnt lgkmcnt(0)" ::: "memory");

            // ---- O += P . V ----
            #pragma unroll
            for (int kc = 0; kc < 2; ++kc) {
                short8 ap[2];
                #pragma unroll
                for (int mt = 0; mt < 2; ++mt)
                    ap[mt] = *(const short8*)&Psm[w][(mt * 16 + l16) * 88 + kc * 32 + quad * 8];
                #pragma unroll
                for (int dt = 0; dt < 4; ++dt) {
                    int row = dt * 16 + l16;
                    short8 bv = *(const short8*)&Vsm[row * 64 + ((kc * 4 + quad) ^ (l16 & 7)) * 8];
                    #pragma unroll
                    for (int mt = 0; mt < 2; ++mt)
                        o[mt][dt] = __builtin_amdgcn_mfma_f32_16x16x32_bf16(ap[mt], bv, o[mt][dt], 0, 0, 0);
                }
            }
        }

        // ---- epilogue: reduce deferred l, scale, store [B,S,D] bf16 ----
        #pragma unroll
        for (int mt = 0; mt < 2; ++mt) {
            #pragma unroll
            for (int r = 0; r < 4; ++r) {
                float lf = li[mt][r];
                lf += __shfl_xor(lf, 1);
                lf += __shfl_xor(lf, 2);
                lf += __shfl_xor(lf, 4);
                lf += __shfl_xor(lf, 8);
                float inv = 1.0f / lf;
                int qg = qmin + mt * 16 + quad * 4 + r;
                #pragma unroll
                for (int dt = 0; dt < 4; ++dt)
                    ao[((size_t)(b * SS + qg)) * DD + h * HD + dt * 16 + l16] = f2bf(o[mt][dt][r] * inv);
            }
        }
    }
}

// ---------------------------------------------------------------------------
extern "C" void kernel_launch(void* const* d_in, const int* in_sizes, int n_in,
                              void* d_out, int out_size, void* d_ws, size_t ws_size,
                              hipStream_t stream) {
    const float* q  = (const float*)d_in[0];
    const float* k  = (const float*)d_in[1];
    const float* v  = (const float*)d_in[2];
    const float* wq = (const float*)d_in[3];
    const float* wk = (const float*)d_in[4];
    const float* wv = (const float*)d_in[5];
    const float* wo = (const float*)d_in[6];
    float* out = (float*)d_out;

    const size_t NEED_BIG = 109051904ull;  // 104 MB
    if (ws_size >= NEED_BIG) {
        // inbf[3*8M] | wbf[4M] | xq[8M] | xk[8M] | xvT[8M]; ao reuses inbf
        ushort_t* inbf = (ushort_t*)d_ws;
        ushort_t* wbf  = inbf + 25165824ull;
        ushort_t* xq   = wbf + 4194304ull;
        ushort_t* xk   = xq + 8388608ull;
        ushort_t* xvT  = xk + 8388608ull;
        ushort_t* ao   = inbf;

        cvt_w<<<4096, 256, 0, stream>>>(wq, wk, wv, wo, wbf);
        cvt3<<<24576, 256, 0, stream>>>(q, k, v, inbf);
        proj3<<<1536, 256, 0, stream>>>(inbf, wbf, xq, xk, xvT);
        attn_kernel<<<512, 256, 0, stream>>>(xq, xk, xvT, ao);
        gemm128<2><<<512, 256, 0, stream>>>(ao, wbf + 3 * 1048576, out);
    } else {
        // 72 MB fallback: wbf[4M] | xq[8M] | xk[8M] | xvT[8M] | xbuf[8M]
        ushort_t* wbf  = (ushort_t*)d_ws;
        ushort_t* xq   = wbf + 4194304ull;
        ushort_t* xk   = xq + 8388608ull;
        ushort_t* xvT  = xk + 8388608ull;
        ushort_t* xbuf = xvT + 8388608ull;

        cvt_w<<<4096, 256, 0, stream>>>(wq, wk, wv, wo, wbf);
        cvt_x<<<8192, 256, 0, stream>>>(q, xbuf);
        gemm128<0><<<512, 256, 0, stream>>>(xbuf, wbf, xq);
        cvt_x<<<8192, 256, 0, stream>>>(k, xbuf);
        gemm128<0><<<512, 256, 0, stream>>>(xbuf, wbf + 1048576, xk);
        cvt_x<<<8192, 256, 0, stream>>>(v, xbuf);
        gemm128<1><<<512, 256, 0, stream>>>(xbuf, wbf + 2 * 1048576, xvT);
        attn_kernel<<<512, 256, 0, stream>>>(xq, xk, xvT, xbuf);
        gemm128<2><<<512, 256, 0, stream>>>(xbuf, wbf + 3 * 1048576, out);
    }
}